// Round 5
// baseline (430.354 us; speedup 1.0000x reference)
//
#include <hip/hip_runtime.h>
#include <hip/hip_cooperative_groups.h>
#include <stdint.h>
#include <stddef.h>

typedef short s8v   __attribute__((ext_vector_type(8)));  // 8 bf16 (4 VGPRs)
typedef float f32x4 __attribute__((ext_vector_type(4)));

union BF8 { s8v v; unsigned short u[8]; };

// truncation split: h = top16(x), residual exact (Sterbenz), l = top16(resid)
__device__ __forceinline__ void split_trunc(float x, unsigned short &h, unsigned short &l) {
  unsigned u = __builtin_bit_cast(unsigned, x);
  h = (unsigned short)(u >> 16);
  float hi = __builtin_bit_cast(float, u & 0xFFFF0000u);
  float r = x - hi;
  l = (unsigned short)(__builtin_bit_cast(unsigned, r) >> 16);
}
__device__ __forceinline__ f32x4 mfma16(s8v a, s8v b, f32x4 c) {
  return __builtin_amdgcn_mfma_f32_16x16x32_bf16(a, b, c, 0, 0, 0);
}
__device__ __forceinline__ void split8(f32x4 a, f32x4 b, s8v &h, s8v &l) {
  BF8 hh, ll;
  #pragma unroll
  for (int i = 0; i < 4; ++i) { split_trunc(a[i], hh.u[i], ll.u[i]); split_trunc(b[i], hh.u[4 + i], ll.u[4 + i]); }
  h = hh.v; l = ll.v;
}

#define BATCH 64
#define NN    4096
#define NX    128
#define NU    32
#define NY    32
#define LPAD  132   // LDS row stride in shorts (bank-conflict tuned)
#define CH    32    // chunk length
#define CPB   128   // chunks per batch

// ---------------- workspace byte offsets ----------------
#define OFF_AH   0
#define OFF_AL   32768
#define OFF_BH   65536
#define OFF_BL   73728
#define OFF_CHS  81920
#define OFF_CLS  90112
#define OFF_DH   98304
#define OFF_DL   100352
#define OFF_G1H  102400
#define OFF_G1L  135168
#define OFF_G2H  167936
#define OFF_G2L  200704
#define OFF_G3H  233472
#define OFF_G3L  266240
#define OFF_V    299008
#define OFF_S    4493312
#define OFF_UH   8687616
#define OFF_UL   25464832
#define OFF_KH   42242048
#define OFF_KL   42504192
#define OFF_S5   42766336
#define OFF_PW   43290624
// end 43749376 (~41.7 MB)

// ---------------- prep: splits of A,B,C,D + u pre-split ----------------
__global__ void k_prep(const float* __restrict__ A, const float* __restrict__ B,
                       const float* __restrict__ C, const float* __restrict__ D,
                       const float* __restrict__ d,
                       unsigned short* Ah, unsigned short* Al,
                       unsigned short* Bh, unsigned short* Bl,
                       unsigned short* Ch, unsigned short* Cl,
                       unsigned short* Dh, unsigned short* Dl,
                       unsigned short* Uh, unsigned short* Ul) {
  const int blk = blockIdx.x;
  if (blk >= 100) {                    // u pre-split: 4096 blocks x 256 thr x 8 floats
    const size_t i0 = ((size_t)(blk - 100) * 256 + threadIdx.x) * 8;
    f32x4 a = *(const f32x4*)(d + i0);
    f32x4 b = *(const f32x4*)(d + i0 + 4);
    s8v h, l; split8(a, b, h, l);
    *(s8v*)(Uh + i0) = h;
    *(s8v*)(Ul + i0) = l;
    return;
  }
  int idx = blk * 256 + threadIdx.x;
  unsigned short h, l;
  if (idx < 16384)      { split_trunc(A[idx], h, l); Ah[idx] = h; Al[idx] = l; }
  else if (idx < 20480) { int i = idx - 16384; split_trunc(B[i], h, l); Bh[i] = h; Bl[i] = l; }
  else if (idx < 24576) { int i = idx - 20480; split_trunc(C[i], h, l); Ch[i] = h; Cl[i] = l; }
  else if (idx < 25600) { int i = idx - 24576; split_trunc(D[i], h, l); Dh[i] = h; Dl[i] = l; }
}

// ---------------- cooperative constants kernel: powers chain + K build + splits ----------------
// PW slots (fp32 128x128): 0:A2 1:A4 2:A8 3:A16 4:A32 5:A64 6:A96
// S (fp32 128x1024): col c = p*32 + j holds (A^p B)[:,j], p ascending 0..31
// K (hi/lo 128x1024): K[i][t*32+j] = (A^(31-t) B)[i][j]  (k-dim order = time-slice t)
__global__ __launch_bounds__(256) void k_const(
    const float* __restrict__ A, const float* __restrict__ B,
    float* __restrict__ PW, float* __restrict__ S,
    unsigned short* G1h, unsigned short* G1l,
    unsigned short* G2h, unsigned short* G2l,
    unsigned short* G3h, unsigned short* G3l,
    unsigned short* Kh, unsigned short* Kl) {
  cooperative_groups::grid_group grid = cooperative_groups::this_grid();
  const int gid = blockIdx.x * 256 + threadIdx.x;   // 64 blocks -> 0..16383
  float* A2  = PW;
  float* A4  = PW + 16384;
  float* A8  = PW + 32768;
  float* A16 = PW + 49152;
  float* A32 = PW + 65536;
  float* A64 = PW + 81920;
  float* A96 = PW + 98304;

  auto mm = [&](const float* X, const float* Y, float* Z) {   // Z = X*Y, 128x128 fp32
    int row = gid >> 7, col = gid & 127;
    const float* xr = X + row * 128;
    float a0 = 0.f, a1 = 0.f;
    #pragma unroll 8
    for (int k = 0; k < 128; k += 2) {
      a0 = fmaf(xr[k],     Y[k * 128 + col],       a0);
      a1 = fmaf(xr[k + 1], Y[(k + 1) * 128 + col], a1);
    }
    Z[gid] = a0 + a1;
  };
  auto sstep = [&](const float* Ap, int half, int sh) {  // S[:,half..2half) = Ap * S[:,0..half)
    for (int idx = gid; idx < 128 * half; idx += 16384) {
      int i = idx >> sh, c = idx & (half - 1);
      const float* ar = Ap + i * 128;
      float acc = 0.f;
      #pragma unroll 8
      for (int k = 0; k < 128; ++k) acc = fmaf(ar[k], S[k * 1024 + c], acc);
      S[i * 1024 + half + c] = acc;
    }
  };
  auto splitbuf = [&](const float* src, unsigned short* dh, unsigned short* dl) {
    unsigned short h, l;
    split_trunc(src[gid], h, l);
    dh[gid] = h; dl[gid] = l;
  };

  // step 0: A2 = A*A ; S[:,0:32) = B ; S[:,32:64) = A*B
  mm(A, A, A2);
  if (gid < 4096) {
    int i = gid >> 5, j = gid & 31;
    S[i * 1024 + j] = B[gid];
    float acc = 0.f;
    #pragma unroll 8
    for (int k = 0; k < 128; ++k) acc = fmaf(A[i * 128 + k], B[k * 32 + j], acc);
    S[i * 1024 + 32 + j] = acc;
  }
  grid.sync();
  mm(A2, A2, A4);   sstep(A2, 64, 6);    grid.sync();
  mm(A4, A4, A8);   sstep(A4, 128, 7);   grid.sync();
  mm(A8, A8, A16);  sstep(A8, 256, 8);   grid.sync();
  mm(A16, A16, A32); sstep(A16, 512, 9); grid.sync();
  // step 5: A64 = A32*A32 ; split G1 ; split K (time-reversed slices)
  mm(A32, A32, A64);
  splitbuf(A32, G1h, G1l);
  for (int idx = gid; idx < 131072; idx += 16384) {
    int i = idx >> 10, kk = idx & 1023;
    int t = kk >> 5, j = kk & 31;
    unsigned short h, l;
    split_trunc(S[i * 1024 + (31 - t) * 32 + j], h, l);
    Kh[idx] = h; Kl[idx] = l;
  }
  grid.sync();
  mm(A64, A32, A96);
  splitbuf(A64, G2h, G2l);
  grid.sync();
  splitbuf(A96, G3h, G3l);
}

// ---------------- v GEMM: V[8192][128] = U_blk[8192][1024] * K^T (3-term hi/lo) ----------------
// replaces the serial pass1 scan: v_c = X_32(chunk c) = sum_t A^(31-t) B u_t
__global__ __launch_bounds__(256, 4) void k_vgemm(
    const unsigned short* __restrict__ Uh, const unsigned short* __restrict__ Ul,
    const unsigned short* __restrict__ Kh, const unsigned short* __restrict__ Kl,
    float* __restrict__ vout) {
  const int tid = threadIdx.x;
  const int w = tid >> 6, l = tid & 63, q = l >> 4, m = l & 15;
  const int g = blockIdx.x;
  const int ch = g * 16 + m, b = ch >> 7, chunk = ch & (CPB - 1);
  const size_t ubase = ((size_t)b * NN + chunk * CH) * NU + q * 8;
  const unsigned short* uhb = Uh + ubase;
  const unsigned short* ulb = Ul + ubase;
  const int n0 = (2 * w) * 16 + m, n1 = (2 * w + 1) * 16 + m;
  const unsigned short* kh0 = Kh + n0 * 1024 + q * 8;
  const unsigned short* kl0 = Kl + n0 * 1024 + q * 8;
  const unsigned short* kh1 = Kh + n1 * 1024 + q * 8;
  const unsigned short* kl1 = Kl + n1 * 1024 + q * 8;

  f32x4 a00 = {0,0,0,0}, a01 = {0,0,0,0}, a02 = {0,0,0,0};
  f32x4 a10 = {0,0,0,0}, a11 = {0,0,0,0}, a12 = {0,0,0,0};
  #pragma unroll 4
  for (int t = 0; t < 32; ++t) {
    s8v uh  = *(const s8v*)(uhb + t * 32);
    s8v ul  = *(const s8v*)(ulb + t * 32);
    s8v k0h = *(const s8v*)(kh0 + t * 32);
    s8v k0l = *(const s8v*)(kl0 + t * 32);
    s8v k1h = *(const s8v*)(kh1 + t * 32);
    s8v k1l = *(const s8v*)(kl1 + t * 32);
    a00 = mfma16(uh, k0h, a00);
    a01 = mfma16(ul, k0h, a01);
    a02 = mfma16(uh, k0l, a02);
    a10 = mfma16(uh, k1h, a10);
    a11 = mfma16(ul, k1h, a11);
    a12 = mfma16(uh, k1l, a12);
  }
  f32x4 acc0 = a00 + a01 + a02;
  f32x4 acc1 = a10 + a11 + a12;
  #pragma unroll
  for (int rr = 0; rr < 4; ++rr) {
    const int row = g * 16 + q * 4 + rr;
    vout[(size_t)row * 128 + n0] = acc0[rr];
    vout[(size_t)row * 128 + n1] = acc1[rr];
  }
}

// ---------------- carry: s_c = v_{c-1} + A^32 v_{c-2} + A^64 v_{c-3} + A^96 v_{c-4} ----------------
__global__ __launch_bounds__(256, 2) void k_carry(
    const unsigned short* __restrict__ G1h, const unsigned short* __restrict__ G1l,
    const unsigned short* __restrict__ G2h, const unsigned short* __restrict__ G2l,
    const unsigned short* __restrict__ G3h, const unsigned short* __restrict__ G3l,
    const float* __restrict__ v, float* __restrict__ sout) {
  const int tid = threadIdx.x;
  const int w = tid >> 6, l = tid & 63, q = l >> 4, m = l & 15;
  const int g = blockIdx.x;
  const int chm = g * 16 + m, cm = chm & (CPB - 1);

  f32x4 a[2];
  a[0] = (f32x4){0.f,0.f,0.f,0.f};
  a[1] = (f32x4){0.f,0.f,0.f,0.f};

#define CARRY_TERM(GH, GL, DELTA)                                              \
  {                                                                            \
    const s8v zero = {0,0,0,0,0,0,0,0};                                        \
    s8v vh[4], vl[4];                                                          \
    _Pragma("unroll")                                                          \
    for (int kt = 0; kt < 4; ++kt) {                                           \
      if (cm >= DELTA) {                                                       \
        const float* vp = v + (size_t)(chm - DELTA) * NX + kt * 32 + q * 8;    \
        split8(*(const f32x4*)vp, *(const f32x4*)(vp + 4), vh[kt], vl[kt]);    \
      } else { vh[kt] = zero; vl[kt] = zero; }                                 \
    }                                                                          \
    _Pragma("unroll")                                                          \
    for (int t2 = 0; t2 < 2; ++t2) {                                           \
      const int n = (2 * w + t2) * 16 + m;                                     \
      _Pragma("unroll")                                                        \
      for (int kt = 0; kt < 4; ++kt) {                                         \
        const int k0 = kt * 32 + q * 8;                                        \
        s8v gh = *(const s8v*)(GH + n * NX + k0);                              \
        s8v gl = *(const s8v*)(GL + n * NX + k0);                              \
        a[t2] = mfma16(vh[kt], gh, a[t2]);                                     \
        a[t2] = mfma16(vl[kt], gh, a[t2]);                                     \
        a[t2] = mfma16(vh[kt], gl, a[t2]);                                     \
      }                                                                        \
    }                                                                          \
  }

  CARRY_TERM(G1h, G1l, 2)
  CARRY_TERM(G2h, G2l, 3)
  CARRY_TERM(G3h, G3l, 4)
#undef CARRY_TERM

  #pragma unroll
  for (int t2 = 0; t2 < 2; ++t2) {
    const int col = (2 * w + t2) * 16 + m;
    #pragma unroll
    for (int rr = 0; rr < 4; ++rr) {
      const int chr = g * 16 + q * 4 + rr, cr = chr & (CPB - 1);
      float sv = 0.f;
      if (cr >= 1) sv = a[t2][rr] + v[(size_t)(chr - 1) * NX + col];
      sout[(size_t)chr * NX + col] = sv;
    }
  }
}

// ---------------- pass 2 fused: A-only two-phase scan, writes all x and all y ----------------
__global__ __launch_bounds__(256, 2) void k_scan2(
    const unsigned short* __restrict__ Uh, const unsigned short* __restrict__ Ul,
    const float* __restrict__ s,
    const unsigned short* __restrict__ Ah, const unsigned short* __restrict__ Al,
    const unsigned short* __restrict__ Bh, const unsigned short* __restrict__ Bl,
    const unsigned short* __restrict__ Ch, const unsigned short* __restrict__ Cl,
    const unsigned short* __restrict__ Dh, const unsigned short* __restrict__ Dl,
    float* __restrict__ yout, float* __restrict__ xout) {
  __shared__ unsigned short Eh[16][LPAD];
  __shared__ unsigned short El[16][LPAD];
  __shared__ unsigned short Oh[16][LPAD];
  __shared__ unsigned short Ol[16][LPAD];
  const int tid = threadIdx.x;
  const int w = tid >> 6, l = tid & 63, q = l >> 4, m = l & 15;
  const int g = blockIdx.x;

  s8v fAh[2][4], fAl[2][4], fBh[2], fBl[2];
  #pragma unroll
  for (int t2 = 0; t2 < 2; ++t2) {
    const int n = (2 * w + t2) * 16 + m;
    #pragma unroll
    for (int kt = 0; kt < 4; ++kt) {
      const int k0 = kt * 32 + q * 8;
      fAh[t2][kt] = *(const s8v*)(Ah + n * 128 + k0);
      fAl[t2][kt] = *(const s8v*)(Al + n * 128 + k0);
    }
    fBh[t2] = *(const s8v*)(Bh + n * 32 + q * 8);
    fBl[t2] = *(const s8v*)(Bl + n * 32 + q * 8);
  }
  s8v fCh[4], fCl[4], fDh, fDl;
  {
    const int o = (w & 1) * 16 + m;
    #pragma unroll
    for (int kt = 0; kt < 4; ++kt) {
      const int k0 = kt * 32 + q * 8;
      fCh[kt] = *(const s8v*)(Ch + o * 128 + k0);
      fCl[kt] = *(const s8v*)(Cl + o * 128 + k0);
    }
    fDh = *(const s8v*)(Dh + o * 32 + q * 8);
    fDl = *(const s8v*)(Dl + o * 32 + q * 8);
  }

  // init: E = s (chunk start state), write x at j0 = chunk*CH (exact fp32)
  {
    const int lb = tid >> 4, i0 = (tid & 15) * 8;
    const int chS = g * 16 + lb, bS = chS >> 7, cS = chS & (CPB - 1);
    const float* sp = s + (size_t)chS * 128 + i0;
    f32x4 s0 = *(const f32x4*)sp, s1 = *(const f32x4*)(sp + 4);
    s8v hh, ll;
    split8(s0, s1, hh, ll);
    *(s8v*)&Eh[lb][i0] = hh;
    *(s8v*)&El[lb][i0] = ll;
    float* xp = xout + ((size_t)bS * (NN + 1) + (size_t)cS * CH) * NX + i0;
    *(f32x4*)xp = s0;
    *(f32x4*)(xp + 4) = s1;
  }
  __syncthreads();

  const int ch = g * 16 + m, b = ch >> 7, chunk = ch & (CPB - 1);
  const size_t ubase = ((size_t)b * NN + chunk * CH) * NU + q * 8;
  const unsigned short* uhb = Uh + ubase;
  const unsigned short* ulb = Ul + ubase;

  float* xptr[2][4];
  bool xlast[2][4];
  float* yptr[4];
  #pragma unroll
  for (int t2 = 0; t2 < 2; ++t2) {
    const int col = (2 * w + t2) * 16 + m;
    #pragma unroll
    for (int rr = 0; rr < 4; ++rr) {
      const int chX = g * 16 + q * 4 + rr, bX = chX >> 7, cX = chX & (CPB - 1);
      xptr[t2][rr] = xout + ((size_t)bX * (NN + 1) + (size_t)cX * CH + 1) * NX + col;
      xlast[t2][rr] = (cX == CPB - 1);
    }
  }
  #pragma unroll
  for (int rr = 0; rr < 4; ++rr) {
    const int chY = g * 16 + q * 4 + rr, bY = chY >> 7, cY = chY & (CPB - 1);
    yptr[rr] = yout + ((size_t)bY * NN + (size_t)cY * CH) * NY + (w & 1) * 16 + m;
  }

  s8v u0h = *(const s8v*)(uhb),      u0l = *(const s8v*)(ulb);
  s8v u1h = *(const s8v*)(uhb + NU), u1l = *(const s8v*)(ulb + NU);

  #pragma unroll 1
  for (int r = 0; r < 16; ++r) {
    s8v n0h = u0h, n0l = u0l, n1h = u1h, n1l = u1l;
    if (r < 15) {
      const size_t off = (size_t)(2 * r + 2) * NU;
      n0h = *(const s8v*)(uhb + off);      n0l = *(const s8v*)(ulb + off);
      n1h = *(const s8v*)(uhb + off + NU); n1l = *(const s8v*)(ulb + off + NU);
    }
    // ---- phase A: read even state, compute x_odd (+ y_even on waves 0,1) ----
    s8v fXh[4], fXl[4];
    #pragma unroll
    for (int kt = 0; kt < 4; ++kt) {
      fXh[kt] = *(const s8v*)&Eh[m][kt * 32 + q * 8];
      fXl[kt] = *(const s8v*)&El[m][kt * 32 + q * 8];
    }
    f32x4 xo[2];
    #pragma unroll
    for (int t2 = 0; t2 < 2; ++t2) {
      f32x4 a0 = {0.f,0.f,0.f,0.f}, a1 = {0.f,0.f,0.f,0.f}, a2 = {0.f,0.f,0.f,0.f};
      #pragma unroll
      for (int kt = 0; kt < 4; ++kt) a0 = mfma16(fXh[kt], fAh[t2][kt], a0);
      a0 = mfma16(u0h, fBh[t2], a0);
      #pragma unroll
      for (int kt = 0; kt < 4; ++kt) a1 = mfma16(fXl[kt], fAh[t2][kt], a1);
      a1 = mfma16(u0l, fBh[t2], a1);
      #pragma unroll
      for (int kt = 0; kt < 4; ++kt) a2 = mfma16(fXh[kt], fAl[t2][kt], a2);
      a2 = mfma16(u0h, fBl[t2], a2);
      xo[t2] = a0 + a1 + a2;
    }
    if (w < 2) {   // y_even = C x_even + D u0
      f32x4 b0 = {0.f,0.f,0.f,0.f}, b1 = {0.f,0.f,0.f,0.f}, b2 = {0.f,0.f,0.f,0.f};
      #pragma unroll
      for (int kt = 0; kt < 4; ++kt) b0 = mfma16(fXh[kt], fCh[kt], b0);
      b0 = mfma16(u0h, fDh, b0);
      #pragma unroll
      for (int kt = 0; kt < 4; ++kt) b1 = mfma16(fXl[kt], fCh[kt], b1);
      b1 = mfma16(u0l, fDh, b1);
      #pragma unroll
      for (int kt = 0; kt < 4; ++kt) b2 = mfma16(fXh[kt], fCl[kt], b2);
      b2 = mfma16(u0h, fDl, b2);
      f32x4 yv = b0 + b1 + b2;
      #pragma unroll
      for (int rr = 0; rr < 4; ++rr) *(yptr[rr]) = yv[rr];
    }
    #pragma unroll
    for (int t2 = 0; t2 < 2; ++t2) {
      const int col = (2 * w + t2) * 16 + m;
      #pragma unroll
      for (int rr = 0; rr < 4; ++rr) {
        *(xptr[t2][rr]) = xo[t2][rr];
        unsigned short h, lo;
        split_trunc(xo[t2][rr], h, lo);
        Oh[q * 4 + rr][col] = h;
        Ol[q * 4 + rr][col] = lo;
      }
    }
    __syncthreads();

    // ---- phase B: read odd state, compute x_even' (+ y_odd on waves 2,3) ----
    s8v fOh[4], fOl[4];
    #pragma unroll
    for (int kt = 0; kt < 4; ++kt) {
      fOh[kt] = *(const s8v*)&Oh[m][kt * 32 + q * 8];
      fOl[kt] = *(const s8v*)&Ol[m][kt * 32 + q * 8];
    }
    f32x4 xe[2];
    #pragma unroll
    for (int t2 = 0; t2 < 2; ++t2) {
      f32x4 a0 = {0.f,0.f,0.f,0.f}, a1 = {0.f,0.f,0.f,0.f}, a2 = {0.f,0.f,0.f,0.f};
      #pragma unroll
      for (int kt = 0; kt < 4; ++kt) a0 = mfma16(fOh[kt], fAh[t2][kt], a0);
      a0 = mfma16(u1h, fBh[t2], a0);
      #pragma unroll
      for (int kt = 0; kt < 4; ++kt) a1 = mfma16(fOl[kt], fAh[t2][kt], a1);
      a1 = mfma16(u1l, fBh[t2], a1);
      #pragma unroll
      for (int kt = 0; kt < 4; ++kt) a2 = mfma16(fOh[kt], fAl[t2][kt], a2);
      a2 = mfma16(u1h, fBl[t2], a2);
      xe[t2] = a0 + a1 + a2;
    }
    if (w >= 2) {  // y_odd = C x_odd + D u1
      f32x4 c0 = {0.f,0.f,0.f,0.f}, c1 = {0.f,0.f,0.f,0.f}, c2 = {0.f,0.f,0.f,0.f};
      #pragma unroll
      for (int kt = 0; kt < 4; ++kt) c0 = mfma16(fOh[kt], fCh[kt], c0);
      c0 = mfma16(u1h, fDh, c0);
      #pragma unroll
      for (int kt = 0; kt < 4; ++kt) c1 = mfma16(fOl[kt], fCh[kt], c1);
      c1 = mfma16(u1l, fDh, c1);
      #pragma unroll
      for (int kt = 0; kt < 4; ++kt) c2 = mfma16(fOh[kt], fCl[kt], c2);
      c2 = mfma16(u1h, fDl, c2);
      f32x4 yv = c0 + c1 + c2;
      #pragma unroll
      for (int rr = 0; rr < 4; ++rr) *(yptr[rr] + NY) = yv[rr];
    }
    #pragma unroll
    for (int t2 = 0; t2 < 2; ++t2) {
      const int col = (2 * w + t2) * 16 + m;
      #pragma unroll
      for (int rr = 0; rr < 4; ++rr) {
        if (r < 15 || xlast[t2][rr]) *(xptr[t2][rr] + NX) = xe[t2][rr];
        unsigned short h, lo;
        split_trunc(xe[t2][rr], h, lo);
        Eh[q * 4 + rr][col] = h;
        El[q * 4 + rr][col] = lo;
      }
    }
    __syncthreads();

    if (r < 15) {
      u0h = n0h; u0l = n0l; u1h = n1h; u1l = n1l;
      #pragma unroll
      for (int t2 = 0; t2 < 2; ++t2)
        #pragma unroll
        for (int rr = 0; rr < 4; ++rr) xptr[t2][rr] += 2 * NX;
      #pragma unroll
      for (int rr = 0; rr < 4; ++rr) yptr[rr] += 2 * NY;
    }
  }
}

// ---------------- launcher ----------------
extern "C" void kernel_launch(void* const* d_in, const int* in_sizes, int n_in,
                              void* d_out, int out_size, void* d_ws, size_t ws_size,
                              hipStream_t stream) {
  (void)in_sizes; (void)n_in; (void)out_size; (void)ws_size;
  const float* d = (const float*)d_in[0];
  const float* A = (const float*)d_in[1];
  const float* B = (const float*)d_in[2];
  const float* C = (const float*)d_in[3];
  const float* D = (const float*)d_in[4];

  char* ws = (char*)d_ws;
  unsigned short* Ah  = (unsigned short*)(ws + OFF_AH);
  unsigned short* Al  = (unsigned short*)(ws + OFF_AL);
  unsigned short* Bh  = (unsigned short*)(ws + OFF_BH);
  unsigned short* Bl  = (unsigned short*)(ws + OFF_BL);
  unsigned short* Chp = (unsigned short*)(ws + OFF_CHS);
  unsigned short* Clp = (unsigned short*)(ws + OFF_CLS);
  unsigned short* Dhp = (unsigned short*)(ws + OFF_DH);
  unsigned short* Dlp = (unsigned short*)(ws + OFF_DL);
  unsigned short* G1h = (unsigned short*)(ws + OFF_G1H);
  unsigned short* G1l = (unsigned short*)(ws + OFF_G1L);
  unsigned short* G2h = (unsigned short*)(ws + OFF_G2H);
  unsigned short* G2l = (unsigned short*)(ws + OFF_G2L);
  unsigned short* G3h = (unsigned short*)(ws + OFF_G3H);
  unsigned short* G3l = (unsigned short*)(ws + OFF_G3L);
  unsigned short* Uh  = (unsigned short*)(ws + OFF_UH);
  unsigned short* Ul  = (unsigned short*)(ws + OFF_UL);
  unsigned short* Kh  = (unsigned short*)(ws + OFF_KH);
  unsigned short* Kl  = (unsigned short*)(ws + OFF_KL);
  float* S5 = (float*)(ws + OFF_S5);
  float* PW = (float*)(ws + OFF_PW);
  float* V  = (float*)(ws + OFF_V);
  float* S  = (float*)(ws + OFF_S);

  float* yout = (float*)d_out;
  float* xout = yout + (size_t)BATCH * NN * NY;

  k_prep<<<4196, 256, 0, stream>>>(A, B, C, D, d,
                                   Ah, Al, Bh, Bl, Chp, Clp, Dhp, Dlp, Uh, Ul);

  void* cargs[] = {(void*)&A, (void*)&B, (void*)&PW, (void*)&S5,
                   (void*)&G1h, (void*)&G1l, (void*)&G2h, (void*)&G2l,
                   (void*)&G3h, (void*)&G3l, (void*)&Kh, (void*)&Kl};
  hipLaunchCooperativeKernel((const void*)k_const, dim3(64), dim3(256),
                             cargs, 0u, stream);

  k_vgemm<<<512, 256, 0, stream>>>(Uh, Ul, Kh, Kl, V);
  k_carry<<<512, 256, 0, stream>>>(G1h, G1l, G2h, G2l, G3h, G3l, V, S);
  k_scan2<<<512, 256, 0, stream>>>(Uh, Ul, S, Ah, Al, Bh, Bl, Chp, Clp, Dhp, Dlp,
                                   yout, xout);
}

// Round 7
// 319.759 us; speedup vs baseline: 1.3459x; 1.3459x over previous
//
#include <hip/hip_runtime.h>
#include <stdint.h>
#include <stddef.h>

typedef short s8v   __attribute__((ext_vector_type(8)));  // 8 bf16 (4 VGPRs)
typedef float f32x4 __attribute__((ext_vector_type(4)));

union BF8 { s8v v; unsigned short u[8]; };

// truncation split: h = top16(x), residual exact (Sterbenz), l = top16(resid)
__device__ __forceinline__ void split_trunc(float x, unsigned short &h, unsigned short &l) {
  unsigned u = __builtin_bit_cast(unsigned, x);
  h = (unsigned short)(u >> 16);
  float hi = __builtin_bit_cast(float, u & 0xFFFF0000u);
  float r = x - hi;
  l = (unsigned short)(__builtin_bit_cast(unsigned, r) >> 16);
}
__device__ __forceinline__ f32x4 mfma16(s8v a, s8v b, f32x4 c) {
  return __builtin_amdgcn_mfma_f32_16x16x32_bf16(a, b, c, 0, 0, 0);
}
__device__ __forceinline__ void split8(f32x4 a, f32x4 b, s8v &h, s8v &l) {
  BF8 hh, ll;
  #pragma unroll
  for (int i = 0; i < 4; ++i) { split_trunc(a[i], hh.u[i], ll.u[i]); split_trunc(b[i], hh.u[4 + i], ll.u[4 + i]); }
  h = hh.v; l = ll.v;
}

#define BATCH 64
#define NN    4096
#define NX    128
#define NU    32
#define NY    32
#define LPAD  132   // LDS row stride in shorts (bank-conflict tuned)
#define CH    32    // chunk length
#define CPB   128   // chunks per batch

// ---------------- workspace byte offsets ----------------
#define OFF_AH   0
#define OFF_AL   32768
#define OFF_BH   65536
#define OFF_BL   73728
#define OFF_CHS  81920
#define OFF_CLS  90112
#define OFF_DH   98304
#define OFF_DL   100352
#define OFF_G1H  102400
#define OFF_G1L  135168
#define OFF_G2H  167936
#define OFF_G2L  200704
#define OFF_G3H  233472
#define OFF_G3L  266240
#define OFF_V    299008
#define OFF_S    4493312
#define OFF_UH   8687616
#define OFF_UL   25464832
#define OFF_KH   42242048
#define OFF_KL   42504192
#define OFF_S5   42766336
#define OFF_PW   43290624
// end ~43.7 MB

// ---------------- prep: splits of A,B,C,D + u pre-split ----------------
__global__ void k_prep(const float* __restrict__ A, const float* __restrict__ B,
                       const float* __restrict__ C, const float* __restrict__ D,
                       const float* __restrict__ d,
                       unsigned short* Ah, unsigned short* Al,
                       unsigned short* Bh, unsigned short* Bl,
                       unsigned short* Ch, unsigned short* Cl,
                       unsigned short* Dh, unsigned short* Dl,
                       unsigned short* Uh, unsigned short* Ul) {
  const int blk = blockIdx.x;
  if (blk >= 100) {                    // u pre-split: 4096 blocks x 256 thr x 8 floats
    const size_t i0 = ((size_t)(blk - 100) * 256 + threadIdx.x) * 8;
    f32x4 a = *(const f32x4*)(d + i0);
    f32x4 b = *(const f32x4*)(d + i0 + 4);
    s8v h, l; split8(a, b, h, l);
    *(s8v*)(Uh + i0) = h;
    *(s8v*)(Ul + i0) = l;
    return;
  }
  int idx = blk * 256 + threadIdx.x;
  unsigned short h, l;
  if (idx < 16384)      { split_trunc(A[idx], h, l); Ah[idx] = h; Al[idx] = l; }
  else if (idx < 20480) { int i = idx - 16384; split_trunc(B[i], h, l); Bh[i] = h; Bl[i] = l; }
  else if (idx < 24576) { int i = idx - 20480; split_trunc(C[i], h, l); Ch[i] = h; Cl[i] = l; }
  else if (idx < 25600) { int i = idx - 24576; split_trunc(D[i], h, l); Dh[i] = h; Dl[i] = l; }
}

// ---------------- pow0: A2 = A*A ; S[:,0:32)=B ; S[:,32:64)=A*B ----------------
// S (fp32 128x1024): col p*32+j holds (A^p B)[:,j]
__global__ void k_pow0(const float* __restrict__ A, const float* __restrict__ B,
                       float* __restrict__ A2, float* __restrict__ S) {
  const int blk = blockIdx.x;
  if (blk < 64) {
    int gid = blk * 256 + threadIdx.x;
    int row = gid >> 7, col = gid & 127;
    const float* xr = A + row * 128;
    float a0 = 0.f, a1 = 0.f;
    #pragma unroll 8
    for (int k = 0; k < 128; k += 2) {
      a0 = fmaf(xr[k],     A[k * 128 + col],       a0);
      a1 = fmaf(xr[k + 1], A[(k + 1) * 128 + col], a1);
    }
    A2[gid] = a0 + a1;
  } else {                             // 16 blocks: S init
    int gid = (blk - 64) * 256 + threadIdx.x;   // 0..4095
    int i = gid >> 5, j = gid & 31;
    S[i * 1024 + j] = B[gid];
    float acc = 0.f;
    #pragma unroll 8
    for (int k = 0; k < 128; ++k) acc = fmaf(A[i * 128 + k], B[k * 32 + j], acc);
    S[i * 1024 + 32 + j] = acc;
  }
}

// ---------------- powN: Z = X*X (optional split) ; S[:,half..2half) = X*S[:,0..half) ----------------
__global__ void k_powN(const float* __restrict__ X, float* __restrict__ Z,
                       float* __restrict__ S, int half, int sh,
                       unsigned short* Zh, unsigned short* Zl, int writeBF) {
  const int blk = blockIdx.x;
  if (blk < 64) {
    int gid = blk * 256 + threadIdx.x;
    int row = gid >> 7, col = gid & 127;
    const float* xr = X + row * 128;
    float a0 = 0.f, a1 = 0.f;
    #pragma unroll 8
    for (int k = 0; k < 128; k += 2) {
      a0 = fmaf(xr[k],     X[k * 128 + col],       a0);
      a1 = fmaf(xr[k + 1], X[(k + 1) * 128 + col], a1);
    }
    float acc = a0 + a1;
    Z[gid] = acc;
    if (writeBF) { unsigned short h, l; split_trunc(acc, h, l); Zh[gid] = h; Zl[gid] = l; }
  } else {                             // sstep: one element per thread
    int idx = (blk - 64) * 256 + threadIdx.x;   // 0 .. 128*half-1
    int i = idx >> sh, c = idx & (half - 1);
    const float* xr = X + i * 128;
    float a0 = 0.f, a1 = 0.f;
    #pragma unroll 8
    for (int k = 0; k < 128; k += 2) {
      a0 = fmaf(xr[k],     S[k * 1024 + c],       a0);
      a1 = fmaf(xr[k + 1], S[(k + 1) * 1024 + c], a1);
    }
    S[i * 1024 + half + c] = a0 + a1;
  }
}

// ---------------- pow5: A64 = A32*A32 (+G2 split) ; K split from S ----------------
// K (hi/lo 128x1024): K[i][t*32+j] = (A^(31-t) B)[i][j]
__global__ void k_pow5(const float* __restrict__ A32, float* __restrict__ A64,
                       const float* __restrict__ S,
                       unsigned short* G2h, unsigned short* G2l,
                       unsigned short* Kh, unsigned short* Kl) {
  const int blk = blockIdx.x;
  if (blk < 64) {
    int gid = blk * 256 + threadIdx.x;
    int row = gid >> 7, col = gid & 127;
    const float* xr = A32 + row * 128;
    float a0 = 0.f, a1 = 0.f;
    #pragma unroll 8
    for (int k = 0; k < 128; k += 2) {
      a0 = fmaf(xr[k],     A32[k * 128 + col],       a0);
      a1 = fmaf(xr[k + 1], A32[(k + 1) * 128 + col], a1);
    }
    float acc = a0 + a1;
    A64[gid] = acc;
    unsigned short h, l; split_trunc(acc, h, l);
    G2h[gid] = h; G2l[gid] = l;
  } else {                             // 512 blocks: K split (time-reversed slices)
    int idx = (blk - 64) * 256 + threadIdx.x;   // 0..131071
    int i = idx >> 10, kk = idx & 1023;
    int t = kk >> 5, j = kk & 31;
    unsigned short h, l;
    split_trunc(S[i * 1024 + (31 - t) * 32 + j], h, l);
    Kh[idx] = h; Kl[idx] = l;
  }
}

// ---------------- v GEMM: V[8192][128] = U_blk * K^T (3-term hi/lo) ; +G3 build ----------------
__global__ __launch_bounds__(256, 4) void k_vgemm(
    const unsigned short* __restrict__ Uh, const unsigned short* __restrict__ Ul,
    const unsigned short* __restrict__ Kh, const unsigned short* __restrict__ Kl,
    const float* __restrict__ A64, const float* __restrict__ A32,
    unsigned short* G3h, unsigned short* G3l,
    float* __restrict__ vout) {
  const int g = blockIdx.x;
  const int tid = threadIdx.x;
  if (g >= 512) {                      // 64 blocks: G3 = split(A64*A32) elementwise
    int gid = (g - 512) * 256 + tid;
    int row = gid >> 7, col = gid & 127;
    const float* xr = A64 + row * 128;
    float a0 = 0.f, a1 = 0.f;
    #pragma unroll 8
    for (int k = 0; k < 128; k += 2) {
      a0 = fmaf(xr[k],     A32[k * 128 + col],       a0);
      a1 = fmaf(xr[k + 1], A32[(k + 1) * 128 + col], a1);
    }
    unsigned short h, l; split_trunc(a0 + a1, h, l);
    G3h[gid] = h; G3l[gid] = l;
    return;
  }
  const int w = tid >> 6, l = tid & 63, q = l >> 4, m = l & 15;
  const int ch = g * 16 + m, b = ch >> 7, chunk = ch & (CPB - 1);
  const size_t ubase = ((size_t)b * NN + chunk * CH) * NU + q * 8;
  const unsigned short* uhb = Uh + ubase;
  const unsigned short* ulb = Ul + ubase;
  const int n0 = (2 * w) * 16 + m, n1 = (2 * w + 1) * 16 + m;
  const unsigned short* kh0 = Kh + n0 * 1024 + q * 8;
  const unsigned short* kl0 = Kl + n0 * 1024 + q * 8;
  const unsigned short* kh1 = Kh + n1 * 1024 + q * 8;
  const unsigned short* kl1 = Kl + n1 * 1024 + q * 8;

  f32x4 a00 = {0,0,0,0}, a01 = {0,0,0,0}, a02 = {0,0,0,0};
  f32x4 a10 = {0,0,0,0}, a11 = {0,0,0,0}, a12 = {0,0,0,0};
  #pragma unroll 4
  for (int t = 0; t < 32; ++t) {
    s8v uh  = *(const s8v*)(uhb + t * 32);
    s8v ul  = *(const s8v*)(ulb + t * 32);
    s8v k0h = *(const s8v*)(kh0 + t * 32);
    s8v k0l = *(const s8v*)(kl0 + t * 32);
    s8v k1h = *(const s8v*)(kh1 + t * 32);
    s8v k1l = *(const s8v*)(kl1 + t * 32);
    a00 = mfma16(uh, k0h, a00);
    a01 = mfma16(ul, k0h, a01);
    a02 = mfma16(uh, k0l, a02);
    a10 = mfma16(uh, k1h, a10);
    a11 = mfma16(ul, k1h, a11);
    a12 = mfma16(uh, k1l, a12);
  }
  f32x4 acc0 = a00 + a01 + a02;
  f32x4 acc1 = a10 + a11 + a12;
  #pragma unroll
  for (int rr = 0; rr < 4; ++rr) {
    const int row = g * 16 + q * 4 + rr;
    vout[(size_t)row * 128 + n0] = acc0[rr];
    vout[(size_t)row * 128 + n1] = acc1[rr];
  }
}

// ---------------- carry: s_c = v_{c-1} + A^32 v_{c-2} + A^64 v_{c-3} + A^96 v_{c-4} ----------------
__global__ __launch_bounds__(256, 2) void k_carry(
    const unsigned short* __restrict__ G1h, const unsigned short* __restrict__ G1l,
    const unsigned short* __restrict__ G2h, const unsigned short* __restrict__ G2l,
    const unsigned short* __restrict__ G3h, const unsigned short* __restrict__ G3l,
    const float* __restrict__ v, float* __restrict__ sout) {
  const int tid = threadIdx.x;
  const int w = tid >> 6, l = tid & 63, q = l >> 4, m = l & 15;
  const int g = blockIdx.x;
  const int chm = g * 16 + m, cm = chm & (CPB - 1);

  f32x4 a[2];
  a[0] = (f32x4){0.f,0.f,0.f,0.f};
  a[1] = (f32x4){0.f,0.f,0.f,0.f};

#define CARRY_TERM(GH, GL, DELTA)                                              \
  {                                                                            \
    const s8v zero = {0,0,0,0,0,0,0,0};                                        \
    s8v vh[4], vl[4];                                                          \
    _Pragma("unroll")                                                          \
    for (int kt = 0; kt < 4; ++kt) {                                           \
      if (cm >= DELTA) {                                                       \
        const float* vp = v + (size_t)(chm - DELTA) * NX + kt * 32 + q * 8;    \
        split8(*(const f32x4*)vp, *(const f32x4*)(vp + 4), vh[kt], vl[kt]);    \
      } else { vh[kt] = zero; vl[kt] = zero; }                                 \
    }                                                                          \
    _Pragma("unroll")                                                          \
    for (int t2 = 0; t2 < 2; ++t2) {                                           \
      const int n = (2 * w + t2) * 16 + m;                                     \
      _Pragma("unroll")                                                        \
      for (int kt = 0; kt < 4; ++kt) {                                         \
        const int k0 = kt * 32 + q * 8;                                        \
        s8v gh = *(const s8v*)(GH + n * NX + k0);                              \
        s8v gl = *(const s8v*)(GL + n * NX + k0);                              \
        a[t2] = mfma16(vh[kt], gh, a[t2]);                                     \
        a[t2] = mfma16(vl[kt], gh, a[t2]);                                     \
        a[t2] = mfma16(vh[kt], gl, a[t2]);                                     \
      }                                                                        \
    }                                                                          \
  }

  CARRY_TERM(G1h, G1l, 2)
  CARRY_TERM(G2h, G2l, 3)
  CARRY_TERM(G3h, G3l, 4)
#undef CARRY_TERM

  #pragma unroll
  for (int t2 = 0; t2 < 2; ++t2) {
    const int col = (2 * w + t2) * 16 + m;
    #pragma unroll
    for (int rr = 0; rr < 4; ++rr) {
      const int chr = g * 16 + q * 4 + rr, cr = chr & (CPB - 1);
      float sv = 0.f;
      if (cr >= 1) sv = a[t2][rr] + v[(size_t)(chr - 1) * NX + col];
      sout[(size_t)chr * NX + col] = sv;
    }
  }
}

// ---------------- pass 2 fused: A-only two-phase scan, writes all x and all y ----------------
__global__ __launch_bounds__(256, 2) void k_scan2(
    const unsigned short* __restrict__ Uh, const unsigned short* __restrict__ Ul,
    const float* __restrict__ s,
    const unsigned short* __restrict__ Ah, const unsigned short* __restrict__ Al,
    const unsigned short* __restrict__ Bh, const unsigned short* __restrict__ Bl,
    const unsigned short* __restrict__ Ch, const unsigned short* __restrict__ Cl,
    const unsigned short* __restrict__ Dh, const unsigned short* __restrict__ Dl,
    float* __restrict__ yout, float* __restrict__ xout) {
  __shared__ unsigned short Eh[16][LPAD];
  __shared__ unsigned short El[16][LPAD];
  __shared__ unsigned short Oh[16][LPAD];
  __shared__ unsigned short Ol[16][LPAD];
  const int tid = threadIdx.x;
  const int w = tid >> 6, l = tid & 63, q = l >> 4, m = l & 15;
  const int g = blockIdx.x;

  s8v fAh[2][4], fAl[2][4], fBh[2], fBl[2];
  #pragma unroll
  for (int t2 = 0; t2 < 2; ++t2) {
    const int n = (2 * w + t2) * 16 + m;
    #pragma unroll
    for (int kt = 0; kt < 4; ++kt) {
      const int k0 = kt * 32 + q * 8;
      fAh[t2][kt] = *(const s8v*)(Ah + n * 128 + k0);
      fAl[t2][kt] = *(const s8v*)(Al + n * 128 + k0);
    }
    fBh[t2] = *(const s8v*)(Bh + n * 32 + q * 8);
    fBl[t2] = *(const s8v*)(Bl + n * 32 + q * 8);
  }
  s8v fCh[4], fCl[4], fDh, fDl;
  {
    const int o = (w & 1) * 16 + m;
    #pragma unroll
    for (int kt = 0; kt < 4; ++kt) {
      const int k0 = kt * 32 + q * 8;
      fCh[kt] = *(const s8v*)(Ch + o * 128 + k0);
      fCl[kt] = *(const s8v*)(Cl + o * 128 + k0);
    }
    fDh = *(const s8v*)(Dh + o * 32 + q * 8);
    fDl = *(const s8v*)(Dl + o * 32 + q * 8);
  }

  // init: E = s (chunk start state), write x at j0 = chunk*CH (exact fp32)
  {
    const int lb = tid >> 4, i0 = (tid & 15) * 8;
    const int chS = g * 16 + lb, bS = chS >> 7, cS = chS & (CPB - 1);
    const float* sp = s + (size_t)chS * 128 + i0;
    f32x4 s0 = *(const f32x4*)sp, s1 = *(const f32x4*)(sp + 4);
    s8v hh, ll;
    split8(s0, s1, hh, ll);
    *(s8v*)&Eh[lb][i0] = hh;
    *(s8v*)&El[lb][i0] = ll;
    float* xp = xout + ((size_t)bS * (NN + 1) + (size_t)cS * CH) * NX + i0;
    *(f32x4*)xp = s0;
    *(f32x4*)(xp + 4) = s1;
  }
  __syncthreads();

  const int ch = g * 16 + m, b = ch >> 7, chunk = ch & (CPB - 1);
  const size_t ubase = ((size_t)b * NN + chunk * CH) * NU + q * 8;
  const unsigned short* uhb = Uh + ubase;
  const unsigned short* ulb = Ul + ubase;

  float* xptr[2][4];
  bool xlast[2][4];
  float* yptr[4];
  #pragma unroll
  for (int t2 = 0; t2 < 2; ++t2) {
    const int col = (2 * w + t2) * 16 + m;
    #pragma unroll
    for (int rr = 0; rr < 4; ++rr) {
      const int chX = g * 16 + q * 4 + rr, bX = chX >> 7, cX = chX & (CPB - 1);
      xptr[t2][rr] = xout + ((size_t)bX * (NN + 1) + (size_t)cX * CH + 1) * NX + col;
      xlast[t2][rr] = (cX == CPB - 1);
    }
  }
  #pragma unroll
  for (int rr = 0; rr < 4; ++rr) {
    const int chY = g * 16 + q * 4 + rr, bY = chY >> 7, cY = chY & (CPB - 1);
    yptr[rr] = yout + ((size_t)bY * NN + (size_t)cY * CH) * NY + (w & 1) * 16 + m;
  }

  s8v u0h = *(const s8v*)(uhb),      u0l = *(const s8v*)(ulb);
  s8v u1h = *(const s8v*)(uhb + NU), u1l = *(const s8v*)(ulb + NU);

  #pragma unroll 1
  for (int r = 0; r < 16; ++r) {
    s8v n0h = u0h, n0l = u0l, n1h = u1h, n1l = u1l;
    if (r < 15) {
      const size_t off = (size_t)(2 * r + 2) * NU;
      n0h = *(const s8v*)(uhb + off);      n0l = *(const s8v*)(ulb + off);
      n1h = *(const s8v*)(uhb + off + NU); n1l = *(const s8v*)(ulb + off + NU);
    }
    // ---- phase A: read even state, compute x_odd (+ y_even on waves 0,1) ----
    s8v fXh[4], fXl[4];
    #pragma unroll
    for (int kt = 0; kt < 4; ++kt) {
      fXh[kt] = *(const s8v*)&Eh[m][kt * 32 + q * 8];
      fXl[kt] = *(const s8v*)&El[m][kt * 32 + q * 8];
    }
    f32x4 xo[2];
    #pragma unroll
    for (int t2 = 0; t2 < 2; ++t2) {
      f32x4 a0 = {0.f,0.f,0.f,0.f}, a1 = {0.f,0.f,0.f,0.f}, a2 = {0.f,0.f,0.f,0.f};
      #pragma unroll
      for (int kt = 0; kt < 4; ++kt) a0 = mfma16(fXh[kt], fAh[t2][kt], a0);
      a0 = mfma16(u0h, fBh[t2], a0);
      #pragma unroll
      for (int kt = 0; kt < 4; ++kt) a1 = mfma16(fXl[kt], fAh[t2][kt], a1);
      a1 = mfma16(u0l, fBh[t2], a1);
      #pragma unroll
      for (int kt = 0; kt < 4; ++kt) a2 = mfma16(fXh[kt], fAl[t2][kt], a2);
      a2 = mfma16(u0h, fBl[t2], a2);
      xo[t2] = a0 + a1 + a2;
    }
    if (w < 2) {   // y_even = C x_even + D u0
      f32x4 b0 = {0.f,0.f,0.f,0.f}, b1 = {0.f,0.f,0.f,0.f}, b2 = {0.f,0.f,0.f,0.f};
      #pragma unroll
      for (int kt = 0; kt < 4; ++kt) b0 = mfma16(fXh[kt], fCh[kt], b0);
      b0 = mfma16(u0h, fDh, b0);
      #pragma unroll
      for (int kt = 0; kt < 4; ++kt) b1 = mfma16(fXl[kt], fCh[kt], b1);
      b1 = mfma16(u0l, fDh, b1);
      #pragma unroll
      for (int kt = 0; kt < 4; ++kt) b2 = mfma16(fXh[kt], fCl[kt], b2);
      b2 = mfma16(u0h, fDl, b2);
      f32x4 yv = b0 + b1 + b2;
      #pragma unroll
      for (int rr = 0; rr < 4; ++rr) *(yptr[rr]) = yv[rr];
    }
    #pragma unroll
    for (int t2 = 0; t2 < 2; ++t2) {
      const int col = (2 * w + t2) * 16 + m;
      #pragma unroll
      for (int rr = 0; rr < 4; ++rr) {
        *(xptr[t2][rr]) = xo[t2][rr];
        unsigned short h, lo;
        split_trunc(xo[t2][rr], h, lo);
        Oh[q * 4 + rr][col] = h;
        Ol[q * 4 + rr][col] = lo;
      }
    }
    __syncthreads();

    // ---- phase B: read odd state, compute x_even' (+ y_odd on waves 2,3) ----
    s8v fOh[4], fOl[4];
    #pragma unroll
    for (int kt = 0; kt < 4; ++kt) {
      fOh[kt] = *(const s8v*)&Oh[m][kt * 32 + q * 8];
      fOl[kt] = *(const s8v*)&Ol[m][kt * 32 + q * 8];
    }
    f32x4 xe[2];
    #pragma unroll
    for (int t2 = 0; t2 < 2; ++t2) {
      f32x4 a0 = {0.f,0.f,0.f,0.f}, a1 = {0.f,0.f,0.f,0.f}, a2 = {0.f,0.f,0.f,0.f};
      #pragma unroll
      for (int kt = 0; kt < 4; ++kt) a0 = mfma16(fOh[kt], fAh[t2][kt], a0);
      a0 = mfma16(u1h, fBh[t2], a0);
      #pragma unroll
      for (int kt = 0; kt < 4; ++kt) a1 = mfma16(fOl[kt], fAh[t2][kt], a1);
      a1 = mfma16(u1l, fBh[t2], a1);
      #pragma unroll
      for (int kt = 0; kt < 4; ++kt) a2 = mfma16(fOh[kt], fAl[t2][kt], a2);
      a2 = mfma16(u1h, fBl[t2], a2);
      xe[t2] = a0 + a1 + a2;
    }
    if (w >= 2) {  // y_odd = C x_odd + D u1
      f32x4 c0 = {0.f,0.f,0.f,0.f}, c1 = {0.f,0.f,0.f,0.f}, c2 = {0.f,0.f,0.f,0.f};
      #pragma unroll
      for (int kt = 0; kt < 4; ++kt) c0 = mfma16(fOh[kt], fCh[kt], c0);
      c0 = mfma16(u1h, fDh, c0);
      #pragma unroll
      for (int kt = 0; kt < 4; ++kt) c1 = mfma16(fOl[kt], fCh[kt], c1);
      c1 = mfma16(u1l, fDh, c1);
      #pragma unroll
      for (int kt = 0; kt < 4; ++kt) c2 = mfma16(fOh[kt], fCl[kt], c2);
      c2 = mfma16(u1h, fDl, c2);
      f32x4 yv = c0 + c1 + c2;
      #pragma unroll
      for (int rr = 0; rr < 4; ++rr) *(yptr[rr] + NY) = yv[rr];
    }
    #pragma unroll
    for (int t2 = 0; t2 < 2; ++t2) {
      const int col = (2 * w + t2) * 16 + m;
      #pragma unroll
      for (int rr = 0; rr < 4; ++rr) {
        if (r < 15 || xlast[t2][rr]) *(xptr[t2][rr] + NX) = xe[t2][rr];
        unsigned short h, lo;
        split_trunc(xe[t2][rr], h, lo);
        Eh[q * 4 + rr][col] = h;
        El[q * 4 + rr][col] = lo;
      }
    }
    __syncthreads();

    if (r < 15) {
      u0h = n0h; u0l = n0l; u1h = n1h; u1l = n1l;
      #pragma unroll
      for (int t2 = 0; t2 < 2; ++t2)
        #pragma unroll
        for (int rr = 0; rr < 4; ++rr) xptr[t2][rr] += 2 * NX;
      #pragma unroll
      for (int rr = 0; rr < 4; ++rr) yptr[rr] += 2 * NY;
    }
  }
}

// ---------------- launcher ----------------
extern "C" void kernel_launch(void* const* d_in, const int* in_sizes, int n_in,
                              void* d_out, int out_size, void* d_ws, size_t ws_size,
                              hipStream_t stream) {
  (void)in_sizes; (void)n_in; (void)out_size; (void)ws_size;
  const float* d = (const float*)d_in[0];
  const float* A = (const float*)d_in[1];
  const float* B = (const float*)d_in[2];
  const float* C = (const float*)d_in[3];
  const float* D = (const float*)d_in[4];

  char* ws = (char*)d_ws;
  unsigned short* Ah  = (unsigned short*)(ws + OFF_AH);
  unsigned short* Al  = (unsigned short*)(ws + OFF_AL);
  unsigned short* Bh  = (unsigned short*)(ws + OFF_BH);
  unsigned short* Bl  = (unsigned short*)(ws + OFF_BL);
  unsigned short* Chp = (unsigned short*)(ws + OFF_CHS);
  unsigned short* Clp = (unsigned short*)(ws + OFF_CLS);
  unsigned short* Dhp = (unsigned short*)(ws + OFF_DH);
  unsigned short* Dlp = (unsigned short*)(ws + OFF_DL);
  unsigned short* G1h = (unsigned short*)(ws + OFF_G1H);
  unsigned short* G1l = (unsigned short*)(ws + OFF_G1L);
  unsigned short* G2h = (unsigned short*)(ws + OFF_G2H);
  unsigned short* G2l = (unsigned short*)(ws + OFF_G2L);
  unsigned short* G3h = (unsigned short*)(ws + OFF_G3H);
  unsigned short* G3l = (unsigned short*)(ws + OFF_G3L);
  unsigned short* Uh  = (unsigned short*)(ws + OFF_UH);
  unsigned short* Ul  = (unsigned short*)(ws + OFF_UL);
  unsigned short* Kh  = (unsigned short*)(ws + OFF_KH);
  unsigned short* Kl  = (unsigned short*)(ws + OFF_KL);
  float* S5 = (float*)(ws + OFF_S5);   // S: 128x1024 fp32
  float* PW = (float*)(ws + OFF_PW);   // power slots
  float* V  = (float*)(ws + OFF_V);
  float* S  = (float*)(ws + OFF_S);

  float* A2  = PW;
  float* A4  = PW + 16384;
  float* A8  = PW + 32768;
  float* A16 = PW + 49152;
  float* A32 = PW + 65536;
  float* A64 = PW + 81920;

  float* yout = (float*)d_out;
  float* xout = yout + (size_t)BATCH * NN * NY;

  k_prep<<<4196, 256, 0, stream>>>(A, B, C, D, d,
                                   Ah, Al, Bh, Bl, Chp, Clp, Dhp, Dlp, Uh, Ul);
  k_pow0<<<80, 256, 0, stream>>>(A, B, A2, S5);
  k_powN<<<96, 256, 0, stream>>>(A2, A4, S5, 64, 6, nullptr, nullptr, 0);
  k_powN<<<128, 256, 0, stream>>>(A4, A8, S5, 128, 7, nullptr, nullptr, 0);
  k_powN<<<192, 256, 0, stream>>>(A8, A16, S5, 256, 8, nullptr, nullptr, 0);
  k_powN<<<320, 256, 0, stream>>>(A16, A32, S5, 512, 9, G1h, G1l, 1);
  k_pow5<<<576, 256, 0, stream>>>(A32, A64, S5, G2h, G2l, Kh, Kl);

  k_vgemm<<<576, 256, 0, stream>>>(Uh, Ul, Kh, Kl, A64, A32, G3h, G3l, V);
  k_carry<<<512, 256, 0, stream>>>(G1h, G1l, G2h, G2l, G3h, G3l, V, S);
  k_scan2<<<512, 256, 0, stream>>>(Uh, Ul, S, Ah, Al, Bh, Bl, Chp, Clp, Dhp, Dlp,
                                   yout, xout);
}

// Round 8
// 303.342 us; speedup vs baseline: 1.4187x; 1.0541x over previous
//
#include <hip/hip_runtime.h>
#include <stdint.h>
#include <stddef.h>

typedef short s8v   __attribute__((ext_vector_type(8)));  // 8 bf16 (4 VGPRs)
typedef float f32x4 __attribute__((ext_vector_type(4)));

union BF8 { s8v v; unsigned short u[8]; };

// truncation split: h = top16(x), residual exact (Sterbenz), l = top16(resid)
__device__ __forceinline__ void split_trunc(float x, unsigned short &h, unsigned short &l) {
  unsigned u = __builtin_bit_cast(unsigned, x);
  h = (unsigned short)(u >> 16);
  float hi = __builtin_bit_cast(float, u & 0xFFFF0000u);
  float r = x - hi;
  l = (unsigned short)(__builtin_bit_cast(unsigned, r) >> 16);
}
__device__ __forceinline__ f32x4 mfma16(s8v a, s8v b, f32x4 c) {
  return __builtin_amdgcn_mfma_f32_16x16x32_bf16(a, b, c, 0, 0, 0);
}
__device__ __forceinline__ void split8(f32x4 a, f32x4 b, s8v &h, s8v &l) {
  BF8 hh, ll;
  #pragma unroll
  for (int i = 0; i < 4; ++i) { split_trunc(a[i], hh.u[i], ll.u[i]); split_trunc(b[i], hh.u[4 + i], ll.u[4 + i]); }
  h = hh.v; l = ll.v;
}

// LDS-only barrier: waits DS ops, NOT global stores (avoids the vmcnt(0) drain
// __syncthreads() would emit). Stores drain in background; kernel-end fences them.
#define LDS_BARRIER() do {                                   \
    asm volatile("s_waitcnt lgkmcnt(0)" ::: "memory");       \
    __builtin_amdgcn_s_barrier();                            \
    __builtin_amdgcn_sched_barrier(0);                       \
  } while (0)

#define BATCH 64
#define NN    4096
#define NX    128
#define NU    32
#define NY    32
#define LPAD  132   // LDS row stride in shorts (bank-conflict tuned)
#define CH    32    // chunk length
#define CPB   128   // chunks per batch

// ---------------- workspace byte offsets ----------------
#define OFF_AH   0
#define OFF_AL   32768
#define OFF_BH   65536
#define OFF_BL   73728
#define OFF_CHS  81920
#define OFF_CLS  90112
#define OFF_DH   98304
#define OFF_DL   100352
#define OFF_G1H  102400
#define OFF_G1L  135168
#define OFF_G2H  167936
#define OFF_G2L  200704
#define OFF_G3H  233472
#define OFF_G3L  266240
#define OFF_V    299008
#define OFF_S    4493312
#define OFF_KH   8687616
#define OFF_KL   8949760
#define OFF_S5   9211904
#define OFF_PW   9736192
// end ~10.2 MB

// ---------------- pow0: A2 = A*A ; S[:,0:32)=B ; S[:,32:64)=A*B ; A,B,C,D splits ----------------
// S (fp32 128x1024): col p*32+j holds (A^p B)[:,j]
__global__ void k_pow0(const float* __restrict__ A, const float* __restrict__ B,
                       const float* __restrict__ C, const float* __restrict__ D,
                       float* __restrict__ A2, float* __restrict__ S,
                       unsigned short* Ah, unsigned short* Al,
                       unsigned short* Bh, unsigned short* Bl,
                       unsigned short* Ch, unsigned short* Cl,
                       unsigned short* Dh, unsigned short* Dl) {
  const int blk = blockIdx.x;
  if (blk < 64) {                      // A^2
    int gid = blk * 256 + threadIdx.x;
    int row = gid >> 7, col = gid & 127;
    const float* xr = A + row * 128;
    float a0 = 0.f, a1 = 0.f;
    #pragma unroll 8
    for (int k = 0; k < 128; k += 2) {
      a0 = fmaf(xr[k],     A[k * 128 + col],       a0);
      a1 = fmaf(xr[k + 1], A[(k + 1) * 128 + col], a1);
    }
    A2[gid] = a0 + a1;
  } else if (blk < 80) {               // S init: B and A*B
    int gid = (blk - 64) * 256 + threadIdx.x;   // 0..4095
    int i = gid >> 5, j = gid & 31;
    S[i * 1024 + j] = B[gid];
    float acc = 0.f;
    #pragma unroll 8
    for (int k = 0; k < 128; ++k) acc = fmaf(A[i * 128 + k], B[k * 32 + j], acc);
    S[i * 1024 + 32 + j] = acc;
  } else {                             // 100 blocks: splits of A,B,C,D
    int idx = (blk - 80) * 256 + threadIdx.x;   // 0..25599
    unsigned short h, l;
    if (idx < 16384)      { split_trunc(A[idx], h, l); Ah[idx] = h; Al[idx] = l; }
    else if (idx < 20480) { int i = idx - 16384; split_trunc(B[i], h, l); Bh[i] = h; Bl[i] = l; }
    else if (idx < 24576) { int i = idx - 20480; split_trunc(C[i], h, l); Ch[i] = h; Cl[i] = l; }
    else if (idx < 25600) { int i = idx - 24576; split_trunc(D[i], h, l); Dh[i] = h; Dl[i] = l; }
  }
}

// ---------------- powN: Z = X*X (optional split) ; S[:,half..2half) = X*S[:,0..half) ----------------
__global__ void k_powN(const float* __restrict__ X, float* __restrict__ Z,
                       float* __restrict__ S, int half, int sh,
                       unsigned short* Zh, unsigned short* Zl, int writeBF) {
  const int blk = blockIdx.x;
  if (blk < 64) {
    int gid = blk * 256 + threadIdx.x;
    int row = gid >> 7, col = gid & 127;
    const float* xr = X + row * 128;
    float a0 = 0.f, a1 = 0.f;
    #pragma unroll 8
    for (int k = 0; k < 128; k += 2) {
      a0 = fmaf(xr[k],     X[k * 128 + col],       a0);
      a1 = fmaf(xr[k + 1], X[(k + 1) * 128 + col], a1);
    }
    float acc = a0 + a1;
    Z[gid] = acc;
    if (writeBF) { unsigned short h, l; split_trunc(acc, h, l); Zh[gid] = h; Zl[gid] = l; }
  } else {                             // sstep: one element per thread
    int idx = (blk - 64) * 256 + threadIdx.x;   // 0 .. 128*half-1
    int i = idx >> sh, c = idx & (half - 1);
    const float* xr = X + i * 128;
    float a0 = 0.f, a1 = 0.f;
    #pragma unroll 8
    for (int k = 0; k < 128; k += 2) {
      a0 = fmaf(xr[k],     S[k * 1024 + c],       a0);
      a1 = fmaf(xr[k + 1], S[(k + 1) * 1024 + c], a1);
    }
    S[i * 1024 + half + c] = a0 + a1;
  }
}

// ---------------- pow5: A64 = A32*A32 (+G2 split) ; K split from S ----------------
// K (hi/lo 128x1024): K[i][t*32+j] = (A^(31-t) B)[i][j]
__global__ void k_pow5(const float* __restrict__ A32, float* __restrict__ A64,
                       const float* __restrict__ S,
                       unsigned short* G2h, unsigned short* G2l,
                       unsigned short* Kh, unsigned short* Kl) {
  const int blk = blockIdx.x;
  if (blk < 64) {
    int gid = blk * 256 + threadIdx.x;
    int row = gid >> 7, col = gid & 127;
    const float* xr = A32 + row * 128;
    float a0 = 0.f, a1 = 0.f;
    #pragma unroll 8
    for (int k = 0; k < 128; k += 2) {
      a0 = fmaf(xr[k],     A32[k * 128 + col],       a0);
      a1 = fmaf(xr[k + 1], A32[(k + 1) * 128 + col], a1);
    }
    float acc = a0 + a1;
    A64[gid] = acc;
    unsigned short h, l; split_trunc(acc, h, l);
    G2h[gid] = h; G2l[gid] = l;
  } else {                             // 512 blocks: K split (time-reversed slices)
    int idx = (blk - 64) * 256 + threadIdx.x;   // 0..131071
    int i = idx >> 10, kk = idx & 1023;
    int t = kk >> 5, j = kk & 31;
    unsigned short h, l;
    split_trunc(S[i * 1024 + (31 - t) * 32 + j], h, l);
    Kh[idx] = h; Kl[idx] = l;
  }
}

// ---------------- v GEMM: V[8192][128] = U_blk * K^T (3-term hi/lo, d read direct) ; +G3 ----------------
__global__ __launch_bounds__(256, 4) void k_vgemm(
    const float* __restrict__ d,
    const unsigned short* __restrict__ Kh, const unsigned short* __restrict__ Kl,
    const float* __restrict__ A64, const float* __restrict__ A32,
    unsigned short* G3h, unsigned short* G3l,
    float* __restrict__ vout) {
  const int g = blockIdx.x;
  const int tid = threadIdx.x;
  if (g >= 512) {                      // 64 blocks: G3 = split(A64*A32) elementwise
    int gid = (g - 512) * 256 + tid;
    int row = gid >> 7, col = gid & 127;
    const float* xr = A64 + row * 128;
    float a0 = 0.f, a1 = 0.f;
    #pragma unroll 8
    for (int k = 0; k < 128; k += 2) {
      a0 = fmaf(xr[k],     A32[k * 128 + col],       a0);
      a1 = fmaf(xr[k + 1], A32[(k + 1) * 128 + col], a1);
    }
    unsigned short h, l; split_trunc(a0 + a1, h, l);
    G3h[gid] = h; G3l[gid] = l;
    return;
  }
  const int w = tid >> 6, l = tid & 63, q = l >> 4, m = l & 15;
  const int ch = g * 16 + m, b = ch >> 7, chunk = ch & (CPB - 1);
  const float* db = d + ((size_t)b * NN + chunk * CH) * NU + q * 8;
  const int n0 = (2 * w) * 16 + m, n1 = (2 * w + 1) * 16 + m;
  const unsigned short* kh0 = Kh + n0 * 1024 + q * 8;
  const unsigned short* kl0 = Kl + n0 * 1024 + q * 8;
  const unsigned short* kh1 = Kh + n1 * 1024 + q * 8;
  const unsigned short* kl1 = Kl + n1 * 1024 + q * 8;

  f32x4 a00 = {0,0,0,0}, a01 = {0,0,0,0}, a02 = {0,0,0,0};
  f32x4 a10 = {0,0,0,0}, a11 = {0,0,0,0}, a12 = {0,0,0,0};
  #pragma unroll 4
  for (int t = 0; t < 32; ++t) {
    f32x4 c0 = *(const f32x4*)(db + t * 32);
    f32x4 c1 = *(const f32x4*)(db + t * 32 + 4);
    s8v uh, ul; split8(c0, c1, uh, ul);
    s8v k0h = *(const s8v*)(kh0 + t * 32);
    s8v k0l = *(const s8v*)(kl0 + t * 32);
    s8v k1h = *(const s8v*)(kh1 + t * 32);
    s8v k1l = *(const s8v*)(kl1 + t * 32);
    a00 = mfma16(uh, k0h, a00);
    a01 = mfma16(ul, k0h, a01);
    a02 = mfma16(uh, k0l, a02);
    a10 = mfma16(uh, k1h, a10);
    a11 = mfma16(ul, k1h, a11);
    a12 = mfma16(uh, k1l, a12);
  }
  f32x4 acc0 = a00 + a01 + a02;
  f32x4 acc1 = a10 + a11 + a12;
  #pragma unroll
  for (int rr = 0; rr < 4; ++rr) {
    const int row = g * 16 + q * 4 + rr;
    vout[(size_t)row * 128 + n0] = acc0[rr];
    vout[(size_t)row * 128 + n1] = acc1[rr];
  }
}

// ---------------- carry: s_c = v_{c-1} + A^32 v_{c-2} + A^64 v_{c-3} + A^96 v_{c-4} ----------------
__global__ __launch_bounds__(256, 2) void k_carry(
    const unsigned short* __restrict__ G1h, const unsigned short* __restrict__ G1l,
    const unsigned short* __restrict__ G2h, const unsigned short* __restrict__ G2l,
    const unsigned short* __restrict__ G3h, const unsigned short* __restrict__ G3l,
    const float* __restrict__ v, float* __restrict__ sout) {
  const int tid = threadIdx.x;
  const int w = tid >> 6, l = tid & 63, q = l >> 4, m = l & 15;
  const int g = blockIdx.x;
  const int chm = g * 16 + m, cm = chm & (CPB - 1);

  f32x4 a[2];
  a[0] = (f32x4){0.f,0.f,0.f,0.f};
  a[1] = (f32x4){0.f,0.f,0.f,0.f};

#define CARRY_TERM(GH, GL, DELTA)                                              \
  {                                                                            \
    const s8v zero = {0,0,0,0,0,0,0,0};                                        \
    s8v vh[4], vl[4];                                                          \
    _Pragma("unroll")                                                          \
    for (int kt = 0; kt < 4; ++kt) {                                           \
      if (cm >= DELTA) {                                                       \
        const float* vp = v + (size_t)(chm - DELTA) * NX + kt * 32 + q * 8;    \
        split8(*(const f32x4*)vp, *(const f32x4*)(vp + 4), vh[kt], vl[kt]);    \
      } else { vh[kt] = zero; vl[kt] = zero; }                                 \
    }                                                                          \
    _Pragma("unroll")                                                          \
    for (int t2 = 0; t2 < 2; ++t2) {                                           \
      const int n = (2 * w + t2) * 16 + m;                                     \
      _Pragma("unroll")                                                        \
      for (int kt = 0; kt < 4; ++kt) {                                         \
        const int k0 = kt * 32 + q * 8;                                        \
        s8v gh = *(const s8v*)(GH + n * NX + k0);                              \
        s8v gl = *(const s8v*)(GL + n * NX + k0);                              \
        a[t2] = mfma16(vh[kt], gh, a[t2]);                                     \
        a[t2] = mfma16(vl[kt], gh, a[t2]);                                     \
        a[t2] = mfma16(vh[kt], gl, a[t2]);                                     \
      }                                                                        \
    }                                                                          \
  }

  CARRY_TERM(G1h, G1l, 2)
  CARRY_TERM(G2h, G2l, 3)
  CARRY_TERM(G3h, G3l, 4)
#undef CARRY_TERM

  #pragma unroll
  for (int t2 = 0; t2 < 2; ++t2) {
    const int col = (2 * w + t2) * 16 + m;
    #pragma unroll
    for (int rr = 0; rr < 4; ++rr) {
      const int chr = g * 16 + q * 4 + rr, cr = chr & (CPB - 1);
      float sv = 0.f;
      if (cr >= 1) sv = a[t2][rr] + v[(size_t)(chr - 1) * NX + col];
      sout[(size_t)chr * NX + col] = sv;
    }
  }
}

// ---------------- pass 2 fused: A-only two-phase scan, writes all x and all y ----------------
// Uses LDS_BARRIER (no global-store drain per phase).
__global__ __launch_bounds__(256, 2) void k_scan2(
    const float* __restrict__ d, const float* __restrict__ s,
    const unsigned short* __restrict__ Ah, const unsigned short* __restrict__ Al,
    const unsigned short* __restrict__ Bh, const unsigned short* __restrict__ Bl,
    const unsigned short* __restrict__ Ch, const unsigned short* __restrict__ Cl,
    const unsigned short* __restrict__ Dh, const unsigned short* __restrict__ Dl,
    float* __restrict__ yout, float* __restrict__ xout) {
  __shared__ unsigned short Eh[16][LPAD];
  __shared__ unsigned short El[16][LPAD];
  __shared__ unsigned short Oh[16][LPAD];
  __shared__ unsigned short Ol[16][LPAD];
  const int tid = threadIdx.x;
  const int w = tid >> 6, l = tid & 63, q = l >> 4, m = l & 15;
  const int g = blockIdx.x;

  s8v fAh[2][4], fAl[2][4], fBh[2], fBl[2];
  #pragma unroll
  for (int t2 = 0; t2 < 2; ++t2) {
    const int n = (2 * w + t2) * 16 + m;
    #pragma unroll
    for (int kt = 0; kt < 4; ++kt) {
      const int k0 = kt * 32 + q * 8;
      fAh[t2][kt] = *(const s8v*)(Ah + n * 128 + k0);
      fAl[t2][kt] = *(const s8v*)(Al + n * 128 + k0);
    }
    fBh[t2] = *(const s8v*)(Bh + n * 32 + q * 8);
    fBl[t2] = *(const s8v*)(Bl + n * 32 + q * 8);
  }
  s8v fCh[4], fCl[4], fDh, fDl;
  {
    const int o = (w & 1) * 16 + m;
    #pragma unroll
    for (int kt = 0; kt < 4; ++kt) {
      const int k0 = kt * 32 + q * 8;
      fCh[kt] = *(const s8v*)(Ch + o * 128 + k0);
      fCl[kt] = *(const s8v*)(Cl + o * 128 + k0);
    }
    fDh = *(const s8v*)(Dh + o * 32 + q * 8);
    fDl = *(const s8v*)(Dl + o * 32 + q * 8);
  }

  // init: E = s (chunk start state), write x at j0 = chunk*CH (exact fp32)
  {
    const int lb = tid >> 4, i0 = (tid & 15) * 8;
    const int chS = g * 16 + lb, bS = chS >> 7, cS = chS & (CPB - 1);
    const float* sp = s + (size_t)chS * 128 + i0;
    f32x4 s0 = *(const f32x4*)sp, s1 = *(const f32x4*)(sp + 4);
    s8v hh, ll;
    split8(s0, s1, hh, ll);
    *(s8v*)&Eh[lb][i0] = hh;
    *(s8v*)&El[lb][i0] = ll;
    float* xp = xout + ((size_t)bS * (NN + 1) + (size_t)cS * CH) * NX + i0;
    *(f32x4*)xp = s0;
    *(f32x4*)(xp + 4) = s1;
  }
  LDS_BARRIER();

  const int ch = g * 16 + m, b = ch >> 7, chunk = ch & (CPB - 1);
  const float* ubase = d + ((size_t)b * NN + chunk * CH) * NU + q * 8;

  float* xptr[2][4];
  bool xlast[2][4];
  float* yptr[4];
  #pragma unroll
  for (int t2 = 0; t2 < 2; ++t2) {
    const int col = (2 * w + t2) * 16 + m;
    #pragma unroll
    for (int rr = 0; rr < 4; ++rr) {
      const int chX = g * 16 + q * 4 + rr, bX = chX >> 7, cX = chX & (CPB - 1);
      xptr[t2][rr] = xout + ((size_t)bX * (NN + 1) + (size_t)cX * CH + 1) * NX + col;
      xlast[t2][rr] = (cX == CPB - 1);
    }
  }
  #pragma unroll
  for (int rr = 0; rr < 4; ++rr) {
    const int chY = g * 16 + q * 4 + rr, bY = chY >> 7, cY = chY & (CPB - 1);
    yptr[rr] = yout + ((size_t)bY * NN + (size_t)cY * CH) * NY + (w & 1) * 16 + m;
  }

  f32x4 cu[4];
  cu[0] = *(const f32x4*)(ubase);      cu[1] = *(const f32x4*)(ubase + 4);
  cu[2] = *(const f32x4*)(ubase + 32); cu[3] = *(const f32x4*)(ubase + 36);

  #pragma unroll 1
  for (int r = 0; r < 16; ++r) {
    f32x4 nu0 = cu[0], nu1 = cu[1], nu2 = cu[2], nu3 = cu[3];
    if (r < 15) {
      const float* up = ubase + (size_t)(2 * r + 2) * NU;
      nu0 = *(const f32x4*)up;        nu1 = *(const f32x4*)(up + 4);
      nu2 = *(const f32x4*)(up + 32); nu3 = *(const f32x4*)(up + 36);
    }
    // ---- phase A: read even state, compute x_odd (+ y_even on waves 0,1) ----
    s8v u0h, u0l;
    split8(cu[0], cu[1], u0h, u0l);
    s8v fXh[4], fXl[4];
    #pragma unroll
    for (int kt = 0; kt < 4; ++kt) {
      fXh[kt] = *(const s8v*)&Eh[m][kt * 32 + q * 8];
      fXl[kt] = *(const s8v*)&El[m][kt * 32 + q * 8];
    }
    f32x4 xo[2];
    #pragma unroll
    for (int t2 = 0; t2 < 2; ++t2) {
      f32x4 a0 = {0.f,0.f,0.f,0.f}, a1 = {0.f,0.f,0.f,0.f}, a2 = {0.f,0.f,0.f,0.f};
      #pragma unroll
      for (int kt = 0; kt < 4; ++kt) a0 = mfma16(fXh[kt], fAh[t2][kt], a0);
      a0 = mfma16(u0h, fBh[t2], a0);
      #pragma unroll
      for (int kt = 0; kt < 4; ++kt) a1 = mfma16(fXl[kt], fAh[t2][kt], a1);
      a1 = mfma16(u0l, fBh[t2], a1);
      #pragma unroll
      for (int kt = 0; kt < 4; ++kt) a2 = mfma16(fXh[kt], fAl[t2][kt], a2);
      a2 = mfma16(u0h, fBl[t2], a2);
      xo[t2] = a0 + a1 + a2;
    }
    if (w < 2) {   // y_even = C x_even + D u0
      f32x4 b0 = {0.f,0.f,0.f,0.f}, b1 = {0.f,0.f,0.f,0.f}, b2 = {0.f,0.f,0.f,0.f};
      #pragma unroll
      for (int kt = 0; kt < 4; ++kt) b0 = mfma16(fXh[kt], fCh[kt], b0);
      b0 = mfma16(u0h, fDh, b0);
      #pragma unroll
      for (int kt = 0; kt < 4; ++kt) b1 = mfma16(fXl[kt], fCh[kt], b1);
      b1 = mfma16(u0l, fDh, b1);
      #pragma unroll
      for (int kt = 0; kt < 4; ++kt) b2 = mfma16(fXh[kt], fCl[kt], b2);
      b2 = mfma16(u0h, fDl, b2);
      f32x4 yv = b0 + b1 + b2;
      #pragma unroll
      for (int rr = 0; rr < 4; ++rr) *(yptr[rr]) = yv[rr];
    }
    #pragma unroll
    for (int t2 = 0; t2 < 2; ++t2) {
      const int col = (2 * w + t2) * 16 + m;
      #pragma unroll
      for (int rr = 0; rr < 4; ++rr) {
        *(xptr[t2][rr]) = xo[t2][rr];
        unsigned short h, lo;
        split_trunc(xo[t2][rr], h, lo);
        Oh[q * 4 + rr][col] = h;
        Ol[q * 4 + rr][col] = lo;
      }
    }
    LDS_BARRIER();

    // ---- phase B: read odd state, compute x_even' (+ y_odd on waves 2,3) ----
    s8v u1h, u1l;
    split8(cu[2], cu[3], u1h, u1l);
    s8v fOh[4], fOl[4];
    #pragma unroll
    for (int kt = 0; kt < 4; ++kt) {
      fOh[kt] = *(const s8v*)&Oh[m][kt * 32 + q * 8];
      fOl[kt] = *(const s8v*)&Ol[m][kt * 32 + q * 8];
    }
    f32x4 xe[2];
    #pragma unroll
    for (int t2 = 0; t2 < 2; ++t2) {
      f32x4 a0 = {0.f,0.f,0.f,0.f}, a1 = {0.f,0.f,0.f,0.f}, a2 = {0.f,0.f,0.f,0.f};
      #pragma unroll
      for (int kt = 0; kt < 4; ++kt) a0 = mfma16(fOh[kt], fAh[t2][kt], a0);
      a0 = mfma16(u1h, fBh[t2], a0);
      #pragma unroll
      for (int kt = 0; kt < 4; ++kt) a1 = mfma16(fOl[kt], fAh[t2][kt], a1);
      a1 = mfma16(u1l, fBh[t2], a1);
      #pragma unroll
      for (int kt = 0; kt < 4; ++kt) a2 = mfma16(fOh[kt], fAl[t2][kt], a2);
      a2 = mfma16(u1h, fBl[t2], a2);
      xe[t2] = a0 + a1 + a2;
    }
    if (w >= 2) {  // y_odd = C x_odd + D u1
      f32x4 c0 = {0.f,0.f,0.f,0.f}, c1 = {0.f,0.f,0.f,0.f}, c2 = {0.f,0.f,0.f,0.f};
      #pragma unroll
      for (int kt = 0; kt < 4; ++kt) c0 = mfma16(fOh[kt], fCh[kt], c0);
      c0 = mfma16(u1h, fDh, c0);
      #pragma unroll
      for (int kt = 0; kt < 4; ++kt) c1 = mfma16(fOl[kt], fCh[kt], c1);
      c1 = mfma16(u1l, fDh, c1);
      #pragma unroll
      for (int kt = 0; kt < 4; ++kt) c2 = mfma16(fOh[kt], fCl[kt], c2);
      c2 = mfma16(u1h, fDl, c2);
      f32x4 yv = c0 + c1 + c2;
      #pragma unroll
      for (int rr = 0; rr < 4; ++rr) *(yptr[rr] + NY) = yv[rr];
    }
    #pragma unroll
    for (int t2 = 0; t2 < 2; ++t2) {
      const int col = (2 * w + t2) * 16 + m;
      #pragma unroll
      for (int rr = 0; rr < 4; ++rr) {
        if (r < 15 || xlast[t2][rr]) *(xptr[t2][rr] + NX) = xe[t2][rr];
        unsigned short h, lo;
        split_trunc(xe[t2][rr], h, lo);
        Eh[q * 4 + rr][col] = h;
        El[q * 4 + rr][col] = lo;
      }
    }
    LDS_BARRIER();

    if (r < 15) {
      cu[0] = nu0; cu[1] = nu1; cu[2] = nu2; cu[3] = nu3;
      #pragma unroll
      for (int t2 = 0; t2 < 2; ++t2)
        #pragma unroll
        for (int rr = 0; rr < 4; ++rr) xptr[t2][rr] += 2 * NX;
      #pragma unroll
      for (int rr = 0; rr < 4; ++rr) yptr[rr] += 2 * NY;
    }
  }
}

// ---------------- launcher ----------------
extern "C" void kernel_launch(void* const* d_in, const int* in_sizes, int n_in,
                              void* d_out, int out_size, void* d_ws, size_t ws_size,
                              hipStream_t stream) {
  (void)in_sizes; (void)n_in; (void)out_size; (void)ws_size;
  const float* d = (const float*)d_in[0];
  const float* A = (const float*)d_in[1];
  const float* B = (const float*)d_in[2];
  const float* C = (const float*)d_in[3];
  const float* D = (const float*)d_in[4];

  char* ws = (char*)d_ws;
  unsigned short* Ah  = (unsigned short*)(ws + OFF_AH);
  unsigned short* Al  = (unsigned short*)(ws + OFF_AL);
  unsigned short* Bh  = (unsigned short*)(ws + OFF_BH);
  unsigned short* Bl  = (unsigned short*)(ws + OFF_BL);
  unsigned short* Chp = (unsigned short*)(ws + OFF_CHS);
  unsigned short* Clp = (unsigned short*)(ws + OFF_CLS);
  unsigned short* Dhp = (unsigned short*)(ws + OFF_DH);
  unsigned short* Dlp = (unsigned short*)(ws + OFF_DL);
  unsigned short* G1h = (unsigned short*)(ws + OFF_G1H);
  unsigned short* G1l = (unsigned short*)(ws + OFF_G1L);
  unsigned short* G2h = (unsigned short*)(ws + OFF_G2H);
  unsigned short* G2l = (unsigned short*)(ws + OFF_G2L);
  unsigned short* G3h = (unsigned short*)(ws + OFF_G3H);
  unsigned short* G3l = (unsigned short*)(ws + OFF_G3L);
  unsigned short* Kh  = (unsigned short*)(ws + OFF_KH);
  unsigned short* Kl  = (unsigned short*)(ws + OFF_KL);
  float* S5 = (float*)(ws + OFF_S5);   // S: 128x1024 fp32
  float* PW = (float*)(ws + OFF_PW);   // power slots
  float* V  = (float*)(ws + OFF_V);
  float* S  = (float*)(ws + OFF_S);

  float* A2  = PW;
  float* A4  = PW + 16384;
  float* A8  = PW + 32768;
  float* A16 = PW + 49152;
  float* A32 = PW + 65536;
  float* A64 = PW + 81920;

  float* yout = (float*)d_out;
  float* xout = yout + (size_t)BATCH * NN * NY;

  k_pow0<<<180, 256, 0, stream>>>(A, B, C, D, A2, S5,
                                  Ah, Al, Bh, Bl, Chp, Clp, Dhp, Dlp);
  k_powN<<<96, 256, 0, stream>>>(A2, A4, S5, 64, 6, nullptr, nullptr, 0);
  k_powN<<<128, 256, 0, stream>>>(A4, A8, S5, 128, 7, nullptr, nullptr, 0);
  k_powN<<<192, 256, 0, stream>>>(A8, A16, S5, 256, 8, nullptr, nullptr, 0);
  k_powN<<<320, 256, 0, stream>>>(A16, A32, S5, 512, 9, G1h, G1l, 1);
  k_pow5<<<576, 256, 0, stream>>>(A32, A64, S5, G2h, G2l, Kh, Kl);

  k_vgemm<<<576, 256, 0, stream>>>(d, Kh, Kl, A64, A32, G3h, G3l, V);
  k_carry<<<512, 256, 0, stream>>>(G1h, G1l, G2h, G2l, G3h, G3l, V, S);
  k_scan2<<<512, 256, 0, stream>>>(d, S, Ah, Al, Bh, Bl, Chp, Clp, Dhp, Dlp,
                                   yout, xout);
}